// Round 6
// baseline (1136.534 us; speedup 1.0000x reference)
//
#include <hip/hip_runtime.h>
#include <cstdint>
#include <cstddef>

// ---------------------------------------------------------------------------
// TGNN fused pipeline v6.
//  seg_kernel: one block per half-segment (50 rows), 256 thr / 4 waves,
//  wm2 x wn2 wave tiling (wave owns 2 m-tiles x half the N):
//    - p2/p3 accumulator: 2mt x 8nt = 64 regs; p1 (64-col chunks): 16 regs.
//      acc-peak 80 + lean arch fits the (256,3) budget (170 total, ~84+84
//      split) -> 3 blocks/CU x 3 waves/SIMD WITHOUT spill.
//      (R3/R4 lesson: unified VGPR+AGPR file; acc>84 under (256,3) spills.)
//    - LDS 46.4 KB/block (hA h[50x392] + hB h2chunk[50x72]; h3[50x264] and
//      the p3 cross-wave sum buffer overlay dead regions).
//  pack_lds: coalesced LDS-transpose weight repack (old version read 2KB-
//  strided -> 16x overfetch).  head1 (500 blocks) + head2: split head.
// ---------------------------------------------------------------------------

typedef __bf16 bf16;
typedef __attribute__((ext_vector_type(8))) __bf16 bf16x8;
typedef __attribute__((ext_vector_type(4))) float floatx4;

// packed-ws element offsets (bf16 elements)
#define WOFF_AW 0
#define WOFF_BW 8192
#define WOFF_P1 12288
#define WOFF_P2 208896
#define WOFF_P3 339968
#define WOFF_F1 602112
#define WOFF_F2 1126400
#define WOFF_PS 1142784          // partial sums [4000][1024] bf16
#define WOFF_H2 5238784          // h2 [2000][512] bf16

// LDS strides (bf16 elems), %8==0 for 16B rows; (stride/2)%32=4 -> benign
#define LSTR_H  392
#define LSTR_H2 72
#define LSTR_H3 264

static __device__ __forceinline__ floatx4 mfma16(bf16x8 a, bf16x8 b, floatx4 c) {
  return __builtin_amdgcn_mfma_f32_16x16x32_bf16(a, b, c, 0, 0, 0);
}

// ---------------------------------------------------------------------------
// Coalesced weight repack: 32k x 64n tiles through an LDS transpose.
// fp32 [K][N] row-major -> bf16 ((nc*KT+kt)*CW + nl)*32 + kk, CW=128.
// 550 standard tiles + 16 tiles for f2w (CW=32).
// ---------------------------------------------------------------------------
__global__ __launch_bounds__(256) void pack_lds(
    const float* __restrict__ aw, const float* __restrict__ bw,
    const float* __restrict__ p1w, const float* __restrict__ p2w,
    const float* __restrict__ p3w, const float* __restrict__ f1w,
    const float* __restrict__ f2w, bf16* __restrict__ wpk) {
  __shared__ float t[32][65];
  const int tid = threadIdx.x;
  int b = blockIdx.x;

  if (b < 550) {
    const float* src; int dstoff, K, N, tt;
    if (b < 4)        { src = aw;  dstoff = WOFF_AW; K = 64;   N = 128;  tt = b; }
    else if (b < 6)   { src = bw;  dstoff = WOFF_BW; K = 32;   N = 128;  tt = b - 4; }
    else if (b < 102) { src = p1w; dstoff = WOFF_P1; K = 384;  N = 512;  tt = b - 6; }
    else if (b < 166) { src = p2w; dstoff = WOFF_P2; K = 512;  N = 256;  tt = b - 102; }
    else if (b < 294) { src = p3w; dstoff = WOFF_P3; K = 256;  N = 1024; tt = b - 166; }
    else              { src = f1w; dstoff = WOFF_F1; K = 1024; N = 512;  tt = b - 294; }
    const int KT = K >> 5;
    const int kt = tt % KT;
    const int n0 = (tt / KT) * 64;
    // load [32k x 64n] coalesced
    for (int i = tid; i < 2048; i += 256) {
      int r = i >> 6, c = i & 63;
      t[r][c] = src[(size_t)(kt * 32 + r) * N + n0 + c];
    }
    __syncthreads();
    // write contiguous 4KB: dst[nl*32 + kk] = t[kk][nl]
    const int nc = n0 >> 7, nl0 = n0 & 127;
    bf16* dst = wpk + dstoff + ((size_t)(nc * KT + kt) * 128 + nl0) * 32;
    int o = tid * 8;
    int nl = o >> 5, kk = o & 31;
    bf16x8 v;
#pragma unroll
    for (int i = 0; i < 8; ++i) v[i] = (bf16)t[kk + i][nl];
    *(bf16x8*)(dst + nl * 32 + kk) = v;
  } else {
    // f2w: K=512, N=32, CW=32; 16 tiles of 32k x 32n
    const int kt = b - 550;
    for (int i = tid; i < 1024; i += 256) {
      int r = i >> 5, c = i & 31;
      t[r][c] = f2w[(size_t)(kt * 32 + r) * 32 + c];
    }
    __syncthreads();
    if (tid < 128) {
      int o = tid * 8;
      int nl = o >> 5, kk = o & 31;
      bf16x8 v;
#pragma unroll
      for (int i = 0; i < 8; ++i) v[i] = (bf16)t[kk + i][nl];
      *(bf16x8*)(wpk + WOFF_F2 + kt * 1024 + nl * 32 + kk) = v;
    }
  }
}

// ---------------------------------------------------------------------------
// seg_kernel: wm2 x wn2. LDS = hA[50x392] 39.2K + hB[50x72] 7.2K = 46.4K.
// h3[50x264] overlays hA; p3 sum buffer (2x256 fp32) overlays hB.
// Pad rows: A-reads clamp row to 49 (dupes excluded from final sums).
// ---------------------------------------------------------------------------
__global__ __launch_bounds__(256, 3) void seg_kernel(
    const float* __restrict__ pairs, const float* __restrict__ ab,
    const float* __restrict__ bb, const float* __restrict__ p1b,
    const float* __restrict__ p2b, const bf16* __restrict__ wpk,
    bf16* __restrict__ psum) {
  __shared__ __align__(16) bf16 smem[23200];
  bf16* const hA = smem;           // h  [50 x 392]
  bf16* const hB = smem + 19600;   // h2 chunk [50 x 72]
  bf16* const h3 = smem;           // h3 [50 x 264] overlays hA
  float* const sbuf = (float*)(smem + 19600);  // [2][256] overlays hB (p3)

  const int tid = threadIdx.x;
  const int w = tid >> 6;
  const int wmid = w >> 1;          // m-half: rows 0-31 / 32-49
  const int wnid = w & 1;           // n-half
  const int lane = tid & 63;
  const int lm = lane & 15;
  const int lq = lane >> 4;
  const int blk = blockIdx.x;

  int rm[2];
#pragma unroll
  for (int i = 0; i < 2; ++i) rm[i] = min((wmid * 2 + i) * 16 + lm, 49);

  const float* const pb = pairs + (size_t)blk * 8000;  // 50 rows x 160
  const floatx4 fz = {0.f, 0.f, 0.f, 0.f};
  floatx4 acc3[16];
  floatx4 acc4[4];

  // ---------------- embed: a1 / a2 / be -> hA[50,384] -------------------
#pragma unroll
  for (int sub = 0; sub < 3; ++sub) {
    const int acol = sub * 64;
    const int nk = (sub == 2) ? 1 : 2;
    const bf16* wsrc = wpk + ((sub == 2) ? WOFF_BW : WOFF_AW);
    const float* bias = (sub == 2) ? bb : ab;
#pragma unroll
    for (int t = 0; t < 8; ++t) acc3[t] = fz;
    for (int kt = 0; kt < nk; ++kt) {
      bf16x8 bf[4];
#pragma unroll
      for (int j = 0; j < 4; ++j)
        bf[j] = *(const bf16x8*)(wsrc +
                  ((size_t)(kt * 128 + wnid * 64 + j * 16 + lm)) * 32 + lq * 8);
#pragma unroll
      for (int mtl = 0; mtl < 2; ++mtl) {
        const float* pr = pb + rm[mtl] * 160 + acol + kt * 32 + lq * 8;
        float4 u = *(const float4*)pr;
        float4 v = *(const float4*)(pr + 4);
        bf16x8 a = {(bf16)u.x, (bf16)u.y, (bf16)u.z, (bf16)u.w,
                    (bf16)v.x, (bf16)v.y, (bf16)v.z, (bf16)v.w};
#pragma unroll
        for (int j = 0; j < 4; ++j)
          acc3[mtl * 4 + j] = mfma16(a, bf[j], acc3[mtl * 4 + j]);
      }
    }
#pragma unroll
    for (int mtl = 0; mtl < 2; ++mtl)
#pragma unroll
      for (int j = 0; j < 4; ++j) {
        int cl = wnid * 64 + j * 16 + lm;
        float bv = bias[cl];
        floatx4 c = acc3[mtl * 4 + j];
#pragma unroll
        for (int r = 0; r < 4; ++r) {
          int row = (wmid * 2 + mtl) * 16 + lq * 4 + r;
          float vv = c[r] + bv;
          vv = vv > 0.f ? vv : 0.f;
          if (row < 50) hA[row * LSTR_H + sub * 128 + cl] = (bf16)vv;
        }
      }
  }
  __syncthreads();

  // ---- p1 (8 chunks of 64 cols), each fused into p2 K-accumulation ----
#pragma unroll
  for (int t = 0; t < 16; ++t) acc3[t] = fz;

  for (int nc = 0; nc < 8; ++nc) {
#pragma unroll
    for (int t = 0; t < 4; ++t) acc4[t] = fz;
    const int c128 = nc >> 1;
    const int nlb = (nc & 1) * 64 + wnid * 32;
    for (int kt = 0; kt < 12; ++kt) {
      bf16x8 b0 = *(const bf16x8*)(wpk + WOFF_P1 +
                    ((size_t)((c128 * 12 + kt) * 128 + nlb + lm)) * 32 + lq * 8);
      bf16x8 b1 = *(const bf16x8*)(wpk + WOFF_P1 +
                    ((size_t)((c128 * 12 + kt) * 128 + nlb + 16 + lm)) * 32 + lq * 8);
#pragma unroll
      for (int mtl = 0; mtl < 2; ++mtl) {
        bf16x8 a = *(const bf16x8*)(hA + rm[mtl] * LSTR_H + kt * 32 + lq * 8);
        acc4[mtl * 2]     = mfma16(a, b0, acc4[mtl * 2]);
        acc4[mtl * 2 + 1] = mfma16(a, b1, acc4[mtl * 2 + 1]);
      }
    }
    __syncthreads();                  // prior p2 reads of hB done (WAR)
#pragma unroll
    for (int mtl = 0; mtl < 2; ++mtl)
#pragma unroll
      for (int j = 0; j < 2; ++j) {
        int cl = wnid * 32 + j * 16 + lm;
        float bv = p1b[nc * 64 + cl];
        floatx4 c = acc4[mtl * 2 + j];
#pragma unroll
        for (int r = 0; r < 4; ++r) {
          int row = (wmid * 2 + mtl) * 16 + lq * 4 + r;
          float vv = c[r] + bv;
          vv = vv > 0.f ? vv : 0.f;
          if (row < 50) hB[row * LSTR_H2 + cl] = (bf16)vv;
        }
      }
    __syncthreads();                  // hB visible
    // p2 partial over this 64-wide K slice; wave covers cols wnid*128..+127
#pragma unroll
    for (int kt2 = 0; kt2 < 2; ++kt2) {
      bf16x8 bp[8];
#pragma unroll
      for (int s = 0; s < 8; ++s)
        bp[s] = *(const bf16x8*)(wpk + WOFF_P2 +
                  ((size_t)((wnid * 16 + nc * 2 + kt2) * 128 + s * 16 + lm)) * 32 +
                  lq * 8);
#pragma unroll
      for (int mtl = 0; mtl < 2; ++mtl) {
        bf16x8 a = *(const bf16x8*)(hB + rm[mtl] * LSTR_H2 + kt2 * 32 + lq * 8);
#pragma unroll
        for (int s = 0; s < 8; ++s)
          acc3[mtl * 8 + s] = mfma16(a, bp[s], acc3[mtl * 8 + s]);
      }
    }
  }

  // p2 epilogue: h3 = relu(acc3 + p2b) -> h3 (overlays hA; all hA reads done
  // at the nc=7 pre-epilogue barrier; h3 region disjoint from hB).
#pragma unroll
  for (int mtl = 0; mtl < 2; ++mtl)
#pragma unroll
    for (int s = 0; s < 8; ++s) {
      int cl = wnid * 128 + s * 16 + lm;
      float bv = p2b[cl];
      floatx4 c = acc3[mtl * 8 + s];
#pragma unroll
      for (int r = 0; r < 4; ++r) {
        int row = (wmid * 2 + mtl) * 16 + lq * 4 + r;
        float vv = c[r] + bv;
        vv = vv > 0.f ? vv : 0.f;
        if (row < 50) h3[row * LSTR_H3 + cl] = (bf16)vv;
      }
    }
  __syncthreads();

  // ---------- p3 (4 chunks of 256 cols) + masked column sums ------------
  for (int cI = 0; cI < 4; ++cI) {
#pragma unroll
    for (int t = 0; t < 16; ++t) acc3[t] = fz;
    const int pc = 2 * cI + wnid;
    for (int kt = 0; kt < 8; ++kt) {
      bf16x8 bp[8];
#pragma unroll
      for (int s = 0; s < 8; ++s)
        bp[s] = *(const bf16x8*)(wpk + WOFF_P3 +
                  ((size_t)((pc * 8 + kt) * 128 + s * 16 + lm)) * 32 + lq * 8);
#pragma unroll
      for (int mtl = 0; mtl < 2; ++mtl) {
        bf16x8 a = *(const bf16x8*)(h3 + rm[mtl] * LSTR_H3 + kt * 32 + lq * 8);
#pragma unroll
        for (int s = 0; s < 8; ++s)
          acc3[mtl * 8 + s] = mfma16(a, bp[s], acc3[mtl * 8 + s]);
      }
    }
    // masked per-wave column partials; global mt3 (wmid1,mtl1) rows 48,49 only
#pragma unroll
    for (int s = 0; s < 8; ++s) {
      float cs = 0.f;
#pragma unroll
      for (int mtl = 0; mtl < 2; ++mtl) {
        floatx4 cc = acc3[mtl * 8 + s];
        float t4;
        if (wmid == 1 && mtl == 1) t4 = (lq == 0) ? (cc[0] + cc[1]) : 0.f;
        else                       t4 = cc[0] + cc[1] + cc[2] + cc[3];
        cs += t4;
      }
      cs += __shfl_xor(cs, 16, 64);
      cs += __shfl_xor(cs, 32, 64);
      if (lq == 0) sbuf[wmid * 256 + wnid * 128 + s * 16 + lm] = cs;
    }
    __syncthreads();
    if (tid < 256) {
      float tot = sbuf[tid] + sbuf[256 + tid];
      psum[(size_t)blk * 1024 + cI * 256 + tid] = (bf16)tot;
    }
    __syncthreads();                  // sbuf WAR for next chunk
  }
}

// ---------------------------------------------------------------------------
// head1: combine (mean + p3 bias) + f1 chunk. 500 blocks = 125 row-groups
// x 4 col-chunks of 128. 4 waves, wave owns n-tiles 2w, 2w+1.
// ---------------------------------------------------------------------------
__global__ __launch_bounds__(256, 2) void head1_kernel(
    const bf16* __restrict__ wpk, const bf16* __restrict__ psum,
    const int* __restrict__ idxp, const float* __restrict__ p3b,
    const float* __restrict__ f1b, bf16* __restrict__ h2) {
  __shared__ __align__(16) bf16 hp[16 * 1032];

  const int tid = threadIdx.x;
  const int w = tid >> 6;
  const int lane = tid & 63;
  const int lm = lane & 15;
  const int lq = lane >> 4;
  const int rg = blockIdx.x >> 2;
  const int cc = blockIdx.x & 3;
  const int r0 = rg * 16;
  const floatx4 fz = {0.f, 0.f, 0.f, 0.f};

  for (int i = tid; i < 16 * 1024; i += 256) {
    int row = i >> 10;
    int c = i & 1023;
    int seg = r0 + row;
    float s = (float)psum[(size_t)(2 * seg) * 1024 + c] +
              (float)psum[(size_t)(2 * seg + 1) * 1024 + c];
    hp[row * 1032 + c] = (bf16)(s / (float)idxp[seg] + p3b[c]);
  }
  __syncthreads();

  floatx4 a2[2];
  a2[0] = fz; a2[1] = fz;
#pragma unroll 8
  for (int kt = 0; kt < 32; ++kt) {
    bf16x8 a = *(const bf16x8*)(hp + lm * 1032 + kt * 32 + lq * 8);
#pragma unroll
    for (int j = 0; j < 2; ++j) {
      bf16x8 b = *(const bf16x8*)(wpk + WOFF_F1 +
                    ((size_t)((cc * 32 + kt) * 128 + (2 * w + j) * 16 + lm)) * 32 + lq * 8);
      a2[j] = mfma16(a, b, a2[j]);
    }
  }
#pragma unroll
  for (int j = 0; j < 2; ++j) {
    int col = cc * 128 + (2 * w + j) * 16 + lm;
    float bv = f1b[col];
#pragma unroll
    for (int r = 0; r < 4; ++r) {
      float v = a2[j][r] + bv;
      v = v > 0.f ? v : 0.f;
      h2[(size_t)(r0 + lq * 4 + r) * 512 + col] = (bf16)v;
    }
  }
}

// ---------------------------------------------------------------------------
// head2: f2 (relu) + f3. Wave-per-16-rows, 32 blocks x 4 waves.
// ---------------------------------------------------------------------------
__global__ __launch_bounds__(256, 2) void head2_kernel(
    const bf16* __restrict__ wpk, const bf16* __restrict__ h2,
    const float* __restrict__ f2b, const float* __restrict__ f3w,
    const float* __restrict__ f3b, float* __restrict__ out) {
  __shared__ __align__(16) bf16 h3s[4][16 * 40];

  const int tid = threadIdx.x;
  const int w = tid >> 6;
  const int lane = tid & 63;
  const int lm = lane & 15;
  const int lq = lane >> 4;
  const int rg = blockIdx.x * 4 + w;
  if (rg >= 125) return;
  const int r0 = rg * 16;
  const floatx4 fz = {0.f, 0.f, 0.f, 0.f};

  floatx4 c2[2];
  c2[0] = fz; c2[1] = fz;
#pragma unroll
  for (int kt = 0; kt < 16; ++kt) {
    bf16x8 a = *(const bf16x8*)(h2 + (size_t)(r0 + lm) * 512 + kt * 32 + lq * 8);
#pragma unroll
    for (int j = 0; j < 2; ++j) {
      bf16x8 b = *(const bf16x8*)(wpk + WOFF_F2 +
                    ((size_t)(kt * 32 + j * 16 + lm)) * 32 + lq * 8);
      c2[j] = mfma16(a, b, c2[j]);
    }
  }
#pragma unroll
  for (int j = 0; j < 2; ++j) {
    int col = j * 16 + lm;
    float bv = f2b[col];
#pragma unroll
    for (int r = 0; r < 4; ++r) {
      float v = c2[j][r] + bv;
      v = v > 0.f ? v : 0.f;
      h3s[w][(lq * 4 + r) * 40 + col] = (bf16)v;
    }
  }
  float ps = 0.f;
#pragma unroll
  for (int jj = 0; jj < 8; ++jj)
    ps += (float)h3s[w][lm * 40 + lq * 8 + jj] * f3w[lq * 8 + jj];
  ps += __shfl_xor(ps, 16, 64);
  ps += __shfl_xor(ps, 32, 64);
  if (lq == 0) out[r0 + lm] = ps + f3b[0];
}

// ---------------------------------------------------------------------------
extern "C" void kernel_launch(void* const* d_in, const int* in_sizes, int n_in,
                              void* d_out, int out_size, void* d_ws,
                              size_t ws_size, hipStream_t stream) {
  (void)in_sizes; (void)n_in; (void)out_size; (void)ws_size;
  const float* pairs = (const float*)d_in[0];
  const int*   idxp  = (const int*)d_in[1];
  // d_in[2] = ref_feats (unused by the reference)
  const float* aw  = (const float*)d_in[3];
  const float* ab  = (const float*)d_in[4];
  const float* bw  = (const float*)d_in[5];
  const float* bb  = (const float*)d_in[6];
  const float* p1w = (const float*)d_in[7];
  const float* p1b = (const float*)d_in[8];
  const float* p2w = (const float*)d_in[9];
  const float* p2b = (const float*)d_in[10];
  const float* p3w = (const float*)d_in[11];
  const float* p3b = (const float*)d_in[12];
  const float* f1w = (const float*)d_in[13];
  const float* f1b = (const float*)d_in[14];
  const float* f2w = (const float*)d_in[15];
  const float* f2b = (const float*)d_in[16];
  const float* f3w = (const float*)d_in[17];
  const float* f3b = (const float*)d_in[18];

  bf16* wpk = (bf16*)d_ws;

  pack_lds<<<566, 256, 0, stream>>>(aw, bw, p1w, p2w, p3w, f1w, f2w, wpk);
  seg_kernel<<<4000, 256, 0, stream>>>(pairs, ab, bb, p1b, p2b, wpk,
                                       wpk + WOFF_PS);
  head1_kernel<<<500, 256, 0, stream>>>(wpk, wpk + WOFF_PS, idxp, p3b, f1b,
                                        wpk + WOFF_H2);
  head2_kernel<<<32, 256, 0, stream>>>(wpk, wpk + WOFF_H2, f2b, f3w, f3b,
                                       (float*)d_out);
}

// Round 7
// 596.556 us; speedup vs baseline: 1.9052x; 1.9052x over previous
//
#include <hip/hip_runtime.h>
#include <cstdint>
#include <cstddef>

// ---------------------------------------------------------------------------
// TGNN fused pipeline v7 = R2's seg_kernel (best proven: 431 us, VGPR 108,
// no spill) + R6's proven-correct coalesced pack_lds and split head1/head2
// (replaces R5's ~182 us non-seg tail).
// Register lesson (R3/R4/R6): unified VGPR+AGPR file; this fused kernel's
// live set is ~220 regs/wave -> 2 waves/SIMD. Any launch_bounds implying
// less spills accumulators to scratch (WRITE_SIZE explodes). Keep (256,2).
// ---------------------------------------------------------------------------

typedef __bf16 bf16;
typedef __attribute__((ext_vector_type(8))) __bf16 bf16x8;
typedef __attribute__((ext_vector_type(4))) __bf16 bf16x4;
typedef __attribute__((ext_vector_type(4))) float floatx4;

#define GRP 100
#define RH 50           // rows per half-segment

// packed-ws element offsets (bf16 elements)
#define WOFF_AW 0
#define WOFF_BW 8192
#define WOFF_P1 12288
#define WOFF_P2 208896
#define WOFF_P3 339968
#define WOFF_F1 602112
#define WOFF_F2 1126400
#define WOFF_PS 1142784          // partial sums [4000][1024] bf16
#define WOFF_H2 5238784          // h2 [2000][512] bf16

// LDS strides (bf16 elems): %8==0 (16B-aligned b128 rows)
#define LSTR_P  168
#define LSTR_H  392
#define LSTR_H2 136
#define LSTR_H3 264

static __device__ __forceinline__ floatx4 mfma16(bf16x8 a, bf16x8 b, floatx4 c) {
  return __builtin_amdgcn_mfma_f32_16x16x32_bf16(a, b, c, 0, 0, 0);
}

// ---------------------------------------------------------------------------
// Coalesced weight repack: 32k x 64n tiles through an LDS transpose.
// fp32 [K][N] row-major -> bf16 ((nc*KT+kt)*CW + nl)*32 + kk, CW=128.
// 550 standard tiles + 16 tiles for f2w (CW=32). Proven correct in R6.
// ---------------------------------------------------------------------------
__global__ __launch_bounds__(256) void pack_lds(
    const float* __restrict__ aw, const float* __restrict__ bw,
    const float* __restrict__ p1w, const float* __restrict__ p2w,
    const float* __restrict__ p3w, const float* __restrict__ f1w,
    const float* __restrict__ f2w, bf16* __restrict__ wpk) {
  __shared__ float t[32][65];
  const int tid = threadIdx.x;
  int b = blockIdx.x;

  if (b < 550) {
    const float* src; int dstoff, K, N, tt;
    if (b < 4)        { src = aw;  dstoff = WOFF_AW; K = 64;   N = 128;  tt = b; }
    else if (b < 6)   { src = bw;  dstoff = WOFF_BW; K = 32;   N = 128;  tt = b - 4; }
    else if (b < 102) { src = p1w; dstoff = WOFF_P1; K = 384;  N = 512;  tt = b - 6; }
    else if (b < 166) { src = p2w; dstoff = WOFF_P2; K = 512;  N = 256;  tt = b - 102; }
    else if (b < 294) { src = p3w; dstoff = WOFF_P3; K = 256;  N = 1024; tt = b - 166; }
    else              { src = f1w; dstoff = WOFF_F1; K = 1024; N = 512;  tt = b - 294; }
    const int KT = K >> 5;
    const int kt = tt % KT;
    const int n0 = (tt / KT) * 64;
    for (int i = tid; i < 2048; i += 256) {
      int r = i >> 6, c = i & 63;
      t[r][c] = src[(size_t)(kt * 32 + r) * N + n0 + c];
    }
    __syncthreads();
    const int nc = n0 >> 7, nl0 = n0 & 127;
    bf16* dst = wpk + dstoff + ((size_t)(nc * KT + kt) * 128 + nl0) * 32;
    int o = tid * 8;
    int nl = o >> 5, kk = o & 31;
    bf16x8 v;
#pragma unroll
    for (int i = 0; i < 8; ++i) v[i] = (bf16)t[kk + i][nl];
    *(bf16x8*)(dst + nl * 32 + kk) = v;
  } else {
    const int kt = b - 550;
    for (int i = tid; i < 1024; i += 256) {
      int r = i >> 5, c = i & 31;
      t[r][c] = f2w[(size_t)(kt * 32 + r) * 32 + c];
    }
    __syncthreads();
    if (tid < 128) {
      int o = tid * 8;
      int nl = o >> 5, kk = o & 31;
      bf16x8 v;
#pragma unroll
      for (int i = 0; i < 8; ++i) v[i] = (bf16)t[kk + i][nl];
      *(bf16x8*)(wpk + WOFF_F2 + kt * 1024 + nl * 32 + kk) = v;
    }
  }
}

// kstep, 2 B-frags from global: 4 A-reads, 8 MFMA
static __device__ __forceinline__ void kstep2(const bf16* __restrict__ Ab,
                                              int astride, int acol,
                                              const bf16* __restrict__ b0p,
                                              const bf16* __restrict__ b1p,
                                              floatx4* acc, int lm, int lq) {
  bf16x8 b0 = *(const bf16x8*)b0p;
  bf16x8 b1 = *(const bf16x8*)b1p;
#pragma unroll
  for (int mt = 0; mt < 4; ++mt) {
    bf16x8 a = *(const bf16x8*)(Ab + (mt * 16 + lm) * astride + acol + lq * 8);
    acc[mt * 2]     = mfma16(a, b0, acc[mt * 2]);
    acc[mt * 2 + 1] = mfma16(a, b1, acc[mt * 2 + 1]);
  }
}

// kstep, 4 consecutive B-frags from global: 4 A-reads, 16 MFMA
static __device__ __forceinline__ void kstep4(const bf16* __restrict__ Ab,
                                              int astride, int acol,
                                              const bf16* __restrict__ bp,
                                              floatx4* acc, int lm, int lq) {
  bf16x8 bf[4];
#pragma unroll
  for (int j = 0; j < 4; ++j) bf[j] = *(const bf16x8*)(bp + j * 512);
#pragma unroll
  for (int mt = 0; mt < 4; ++mt) {
    bf16x8 a = *(const bf16x8*)(Ab + (mt * 16 + lm) * astride + acol + lq * 8);
#pragma unroll
    for (int j = 0; j < 4; ++j)
      acc[mt * 4 + j] = mfma16(a, bf[j], acc[mt * 4 + j]);
  }
}

// epilogue for 2-N-tile acc: relu(acc+bias) -> LDS
static __device__ __forceinline__ void epi2(const floatx4* acc,
                                            const float* __restrict__ bias,
                                            bf16* dst, int dstride, int w,
                                            int lm, int lq) {
#pragma unroll
  for (int mt = 0; mt < 4; ++mt)
#pragma unroll
    for (int j = 0; j < 2; ++j) {
      int col = (w + 4 * j) * 16 + lm;
      float bv = bias[col];
      floatx4 c = acc[mt * 2 + j];
#pragma unroll
      for (int r = 0; r < 4; ++r) {
        float v = c[r] + bv;
        v = v > 0.f ? v : 0.f;
        dst[(mt * 16 + lq * 4 + r) * dstride + col] = (bf16)v;
      }
    }
}

// ---------------------------------------------------------------------------
// seg_kernel (R2 verbatim): one block per half-segment (50 rows, M=64).
// LDS: hbuf 50176 + pbuf 21504 = 71680 B -> 2 blocks/CU.
// ---------------------------------------------------------------------------
__global__ __launch_bounds__(256, 2) void seg_kernel(
    const float* __restrict__ pairs, const float* __restrict__ ab,
    const float* __restrict__ bb, const float* __restrict__ p1b,
    const float* __restrict__ p2b, const bf16* __restrict__ wpk,
    bf16* __restrict__ psum) {
  __shared__ __align__(16) bf16 hbuf[64 * LSTR_H];  // h[64,384] then h3[64,256]
  __shared__ __align__(16) bf16 pbuf[64 * LSTR_P];  // pairs bf16, then h2 chunk

  const int tid = threadIdx.x;
  const int w = tid >> 6;
  const int lane = tid & 63;
  const int lm = lane & 15;
  const int lq = lane >> 4;
  const int blk = blockIdx.x;

  // ---- stage pairs half-tile [50,160] fp32 -> bf16 LDS, zero pad rows ----
  {
    const float4* src = (const float4*)(pairs + (size_t)blk * (RH * 160));
    for (int i = tid; i < RH * 40; i += 256) {
      int row = i / 40;
      int c4 = (i - row * 40) * 4;
      float4 v = src[i];
      bf16x4 o = {(bf16)v.x, (bf16)v.y, (bf16)v.z, (bf16)v.w};
      *(bf16x4*)(pbuf + row * LSTR_P + c4) = o;
    }
    for (int i = tid; i < 14 * 160; i += 256) {
      int row = RH + i / 160;
      int c = i - (i / 160) * 160;
      pbuf[row * LSTR_P + c] = (bf16)0.0f;
    }
  }
  __syncthreads();

  const floatx4 fz = {0.f, 0.f, 0.f, 0.f};
  floatx4 acc[16];
  floatx4 acc3[16];

  // ---------------- embed: a1 / a2 / be -> hbuf[64,384] ----------------
#pragma unroll
  for (int t = 0; t < 8; ++t) acc[t] = fz;
#pragma unroll
  for (int kt = 0; kt < 2; ++kt)
    kstep2(pbuf, LSTR_P, kt * 32,
           wpk + WOFF_AW + ((size_t)(kt * 128 + w * 16 + lm)) * 32 + lq * 8,
           wpk + WOFF_AW + ((size_t)(kt * 128 + (w + 4) * 16 + lm)) * 32 + lq * 8,
           acc, lm, lq);
  epi2(acc, ab, hbuf, LSTR_H, w, lm, lq);
#pragma unroll
  for (int t = 0; t < 8; ++t) acc[t] = fz;
#pragma unroll
  for (int kt = 0; kt < 2; ++kt)
    kstep2(pbuf, LSTR_P, 64 + kt * 32,
           wpk + WOFF_AW + ((size_t)(kt * 128 + w * 16 + lm)) * 32 + lq * 8,
           wpk + WOFF_AW + ((size_t)(kt * 128 + (w + 4) * 16 + lm)) * 32 + lq * 8,
           acc, lm, lq);
  epi2(acc, ab, hbuf + 128, LSTR_H, w, lm, lq);
#pragma unroll
  for (int t = 0; t < 8; ++t) acc[t] = fz;
  kstep2(pbuf, LSTR_P, 128,
         wpk + WOFF_BW + ((size_t)(w * 16 + lm)) * 32 + lq * 8,
         wpk + WOFF_BW + ((size_t)((w + 4) * 16 + lm)) * 32 + lq * 8,
         acc, lm, lq);
  epi2(acc, bb, hbuf + 256, LSTR_H, w, lm, lq);

  __syncthreads();

  // ------- p1 (4 N-chunks of 128), each fused into p2 K-accumulation -------
#pragma unroll
  for (int t = 0; t < 16; ++t) acc3[t] = fz;

  for (int nc = 0; nc < 4; ++nc) {
#pragma unroll
    for (int t = 0; t < 8; ++t) acc[t] = fz;
#pragma unroll
    for (int kt = 0; kt < 12; ++kt)
      kstep2(hbuf, LSTR_H, kt * 32,
             wpk + WOFF_P1 + ((size_t)((nc * 12 + kt) * 128 + w * 16 + lm)) * 32 + lq * 8,
             wpk + WOFF_P1 + ((size_t)((nc * 12 + kt) * 128 + (w + 4) * 16 + lm)) * 32 + lq * 8,
             acc, lm, lq);
    __syncthreads();                       // prior p2 reads of pbuf done
    epi2(acc, p1b + nc * 128, pbuf, LSTR_H2, w, lm, lq);
    __syncthreads();                       // h2 chunk visible
#pragma unroll
    for (int kt2 = 0; kt2 < 4; ++kt2)
      kstep4(pbuf, LSTR_H2, kt2 * 32,
             wpk + WOFF_P2 +
                 ((size_t)(((w >> 1) * 16 + nc * 4 + kt2) * 128 + (w & 1) * 64 + lm)) * 32 +
                 lq * 8,
             acc3, lm, lq);
  }

  // p2 epilogue: h3 = relu(acc3 + p2b) -> hbuf (stride 264)
#pragma unroll
  for (int mt = 0; mt < 4; ++mt)
#pragma unroll
    for (int s = 0; s < 4; ++s) {
      int cl = w * 64 + s * 16 + lm;
      float bv = p2b[cl];
      floatx4 c = acc3[mt * 4 + s];
#pragma unroll
      for (int r = 0; r < 4; ++r) {
        float v = c[r] + bv;
        v = v > 0.f ? v : 0.f;
        hbuf[(mt * 16 + lq * 4 + r) * LSTR_H3 + cl] = (bf16)v;
      }
    }
  __syncthreads();

  // ---------------- p3 (4 N-chunks of 256) + masked column sums ----------
  const int wn = w >> 1;
  const int wl = (w & 1) * 64;
  for (int c = 0; c < 4; ++c) {
#pragma unroll
    for (int t = 0; t < 16; ++t) acc[t] = fz;
#pragma unroll
    for (int kt = 0; kt < 8; ++kt)
      kstep4(hbuf, LSTR_H3, kt * 32,
             wpk + WOFF_P3 + ((size_t)(((2 * c + wn) * 8 + kt) * 128 + wl + lm)) * 32 + lq * 8,
             acc, lm, lq);
#pragma unroll
    for (int j = 0; j < 4; ++j) {
      float cs = 0.f;
#pragma unroll
      for (int mt = 0; mt < 4; ++mt) {
        floatx4 cc = acc[mt * 4 + j];
        float t4;
        if (mt < 3) t4 = cc[0] + cc[1] + cc[2] + cc[3];
        else        t4 = (lq == 0) ? (cc[0] + cc[1]) : 0.f;
        cs += t4;
      }
      cs += __shfl_xor(cs, 16, 64);
      cs += __shfl_xor(cs, 32, 64);
      if (lq == 0) {
        int col = c * 256 + w * 64 + j * 16 + lm;
        psum[(size_t)blk * 1024 + col] = (bf16)cs;
      }
    }
  }
}

// ---------------------------------------------------------------------------
// head1: combine (mean + p3 bias) + f1 chunk. 500 blocks = 125 row-groups
// x 4 col-chunks of 128. Proven correct in R6.
// ---------------------------------------------------------------------------
__global__ __launch_bounds__(256, 2) void head1_kernel(
    const bf16* __restrict__ wpk, const bf16* __restrict__ psum,
    const int* __restrict__ idxp, const float* __restrict__ p3b,
    const float* __restrict__ f1b, bf16* __restrict__ h2) {
  __shared__ __align__(16) bf16 hp[16 * 1032];

  const int tid = threadIdx.x;
  const int w = tid >> 6;
  const int lane = tid & 63;
  const int lm = lane & 15;
  const int lq = lane >> 4;
  const int rg = blockIdx.x >> 2;
  const int cc = blockIdx.x & 3;
  const int r0 = rg * 16;
  const floatx4 fz = {0.f, 0.f, 0.f, 0.f};

  for (int i = tid; i < 16 * 1024; i += 256) {
    int row = i >> 10;
    int c = i & 1023;
    int seg = r0 + row;
    float s = (float)psum[(size_t)(2 * seg) * 1024 + c] +
              (float)psum[(size_t)(2 * seg + 1) * 1024 + c];
    hp[row * 1032 + c] = (bf16)(s / (float)idxp[seg] + p3b[c]);
  }
  __syncthreads();

  floatx4 a2[2];
  a2[0] = fz; a2[1] = fz;
#pragma unroll 8
  for (int kt = 0; kt < 32; ++kt) {
    bf16x8 a = *(const bf16x8*)(hp + lm * 1032 + kt * 32 + lq * 8);
#pragma unroll
    for (int j = 0; j < 2; ++j) {
      bf16x8 b = *(const bf16x8*)(wpk + WOFF_F1 +
                    ((size_t)((cc * 32 + kt) * 128 + (2 * w + j) * 16 + lm)) * 32 + lq * 8);
      a2[j] = mfma16(a, b, a2[j]);
    }
  }
#pragma unroll
  for (int j = 0; j < 2; ++j) {
    int col = cc * 128 + (2 * w + j) * 16 + lm;
    float bv = f1b[col];
#pragma unroll
    for (int r = 0; r < 4; ++r) {
      float v = a2[j][r] + bv;
      v = v > 0.f ? v : 0.f;
      h2[(size_t)(r0 + lq * 4 + r) * 512 + col] = (bf16)v;
    }
  }
}

// ---------------------------------------------------------------------------
// head2: f2 (relu) + f3. Wave-per-16-rows, 32 blocks x 4 waves.
// ---------------------------------------------------------------------------
__global__ __launch_bounds__(256, 2) void head2_kernel(
    const bf16* __restrict__ wpk, const bf16* __restrict__ h2,
    const float* __restrict__ f2b, const float* __restrict__ f3w,
    const float* __restrict__ f3b, float* __restrict__ out) {
  __shared__ __align__(16) bf16 h3s[4][16 * 40];

  const int tid = threadIdx.x;
  const int w = tid >> 6;
  const int lane = tid & 63;
  const int lm = lane & 15;
  const int lq = lane >> 4;
  const int rg = blockIdx.x * 4 + w;
  if (rg >= 125) return;
  const int r0 = rg * 16;
  const floatx4 fz = {0.f, 0.f, 0.f, 0.f};

  floatx4 c2[2];
  c2[0] = fz; c2[1] = fz;
#pragma unroll
  for (int kt = 0; kt < 16; ++kt) {
    bf16x8 a = *(const bf16x8*)(h2 + (size_t)(r0 + lm) * 512 + kt * 32 + lq * 8);
#pragma unroll
    for (int j = 0; j < 2; ++j) {
      bf16x8 b = *(const bf16x8*)(wpk + WOFF_F2 +
                    ((size_t)(kt * 32 + j * 16 + lm)) * 32 + lq * 8);
      c2[j] = mfma16(a, b, c2[j]);
    }
  }
#pragma unroll
  for (int j = 0; j < 2; ++j) {
    int col = j * 16 + lm;
    float bv = f2b[col];
#pragma unroll
    for (int r = 0; r < 4; ++r) {
      float v = c2[j][r] + bv;
      v = v > 0.f ? v : 0.f;
      h3s[w][(lq * 4 + r) * 40 + col] = (bf16)v;
    }
  }
  float ps = 0.f;
#pragma unroll
  for (int jj = 0; jj < 8; ++jj)
    ps += (float)h3s[w][lm * 40 + lq * 8 + jj] * f3w[lq * 8 + jj];
  ps += __shfl_xor(ps, 16, 64);
  ps += __shfl_xor(ps, 32, 64);
  if (lq == 0) out[r0 + lm] = ps + f3b[0];
}

// ---------------------------------------------------------------------------
extern "C" void kernel_launch(void* const* d_in, const int* in_sizes, int n_in,
                              void* d_out, int out_size, void* d_ws,
                              size_t ws_size, hipStream_t stream) {
  (void)in_sizes; (void)n_in; (void)out_size; (void)ws_size;
  const float* pairs = (const float*)d_in[0];
  const int*   idxp  = (const int*)d_in[1];
  // d_in[2] = ref_feats (unused by the reference)
  const float* aw  = (const float*)d_in[3];
  const float* ab  = (const float*)d_in[4];
  const float* bw  = (const float*)d_in[5];
  const float* bb  = (const float*)d_in[6];
  const float* p1w = (const float*)d_in[7];
  const float* p1b = (const float*)d_in[8];
  const float* p2w = (const float*)d_in[9];
  const float* p2b = (const float*)d_in[10];
  const float* p3w = (const float*)d_in[11];
  const float* p3b = (const float*)d_in[12];
  const float* f1w = (const float*)d_in[13];
  const float* f1b = (const float*)d_in[14];
  const float* f2w = (const float*)d_in[15];
  const float* f2b = (const float*)d_in[16];
  const float* f3w = (const float*)d_in[17];
  const float* f3b = (const float*)d_in[18];

  bf16* wpk = (bf16*)d_ws;

  pack_lds<<<566, 256, 0, stream>>>(aw, bw, p1w, p2w, p3w, f1w, f2w, wpk);
  seg_kernel<<<4000, 256, 0, stream>>>(pairs, ab, bb, p1b, p2b, wpk,
                                       wpk + WOFF_PS);
  head1_kernel<<<500, 256, 0, stream>>>(wpk, wpk + WOFF_PS, idxp, p3b, f1b,
                                        wpk + WOFF_H2);
  head2_kernel<<<32, 256, 0, stream>>>(wpk, wpk + WOFF_H2, f2b, f3w, f3b,
                                       (float*)d_out);
}